// Round 3
// baseline (5413.956 us; speedup 1.0000x reference)
//
#include <hip/hip_runtime.h>
#include <hip/hip_bf16.h>
#include <cstdint>
#include <cstddef>

#define HIDDEN 2048
#define NHEADS 16
#define NKV    8
#define HD     128
#define QS     (NHEADS*HD)      // 2048
#define KVS    (NKV*HD)         // 1024
#define OC     (QS + 2*KVS)     // 4096
#define BB     2
#define SS     2048
#define ROWS   (BB*SS)          // 4096

typedef __bf16 bf16;
typedef __bf16 bf16x8 __attribute__((ext_vector_type(8)));
typedef float  f32x4  __attribute__((ext_vector_type(4)));
typedef float  f32x2  __attribute__((ext_vector_type(2)));
typedef int    i32x4  __attribute__((ext_vector_type(4)));

// ---------------- f32 -> bf16 convert (vectorized) ----------------
__global__ __launch_bounds__(256) void k_cvt(const float* __restrict__ src,
                                             bf16* __restrict__ dst, int n8) {
  int i = blockIdx.x * blockDim.x + threadIdx.x;
  int stride = gridDim.x * blockDim.x;
  for (; i < n8; i += stride) {
    const f32x4* s = (const f32x4*)(src + (size_t)i * 8);
    f32x4 a = s[0], b = s[1];
    bf16x8 o;
    o[0]=(bf16)a[0]; o[1]=(bf16)a[1]; o[2]=(bf16)a[2]; o[3]=(bf16)a[3];
    o[4]=(bf16)b[0]; o[5]=(bf16)b[1]; o[6]=(bf16)b[2]; o[7]=(bf16)b[3];
    *(bf16x8*)(dst + (size_t)i * 8) = o;
  }
}

// ---------------- RoPE cos/sin table: tbl[pos][i] = {cos, sin} ----------------
__global__ __launch_bounds__(256) void k_table(float* __restrict__ tbl) {
  int t = blockIdx.x * blockDim.x + threadIdx.x;   // t < SS*64
  int pos = t >> 6, i = t & 63;
  float freq = powf(10000.0f, -(float)i / 64.0f);
  float ang = (float)pos * freq;
  float sv, cv;
  sincosf(ang, &sv, &cv);
  f32x2 v; v[0] = cv; v[1] = sv;
  ((f32x2*)tbl)[t] = v;
}

// ---------------- async global->LDS helper ----------------
__device__ __forceinline__ void gll16(const void* g, void* l) {
  __builtin_amdgcn_global_load_lds((const __attribute__((address_space(1))) void*)g,
                                   (__attribute__((address_space(3))) void*)l, 16, 0, 0);
}

// ---------------- GEMM: C[M][N] = A[M][K] * Bw[N][K]^T  (bf16 in, f32 accum, OT out) ----------------
template <typename OT>
__global__ __launch_bounds__(256) void k_gemm(const bf16* __restrict__ A,
                                              const bf16* __restrict__ Bw,
                                              OT* __restrict__ C,
                                              int M, int N, int K) {
  const int tid = threadIdx.x;
  const int lane = tid & 63;
  const int w = tid >> 6;
  const int m0 = blockIdx.y * 128, n0 = blockIdx.x * 128;
  __shared__ bf16 As[128 * 32];
  __shared__ bf16 Bs[128 * 32];
  f32x4 acc[4][4] = {};
  const int wm = (w >> 1) * 64, wn = (w & 1) * 64;
  const int lr = lane & 15, lg = lane >> 4;
  const int KT = K >> 5;
  for (int kt = 0; kt < KT; ++kt) {
    __syncthreads();
    for (int i = 0; i < 2; ++i) {
      int c = tid + i * 256;
      int row = c >> 2, kc = c & 3;
      gll16(A + (size_t)(m0 + row) * K + kt * 32 + kc * 8, As + (size_t)(c & ~63) * 8);
      gll16(Bw + (size_t)(n0 + row) * K + kt * 32 + kc * 8, Bs + (size_t)(c & ~63) * 8);
    }
    asm volatile("s_waitcnt vmcnt(0)" ::: "memory");
    __syncthreads();
    bf16x8 af[4], bfv[4];
    for (int i = 0; i < 4; ++i)
      af[i] = *(const bf16x8*)(As + (wm + i * 16 + lr) * 32 + lg * 8);
    for (int j = 0; j < 4; ++j)
      bfv[j] = *(const bf16x8*)(Bs + (wn + j * 16 + lr) * 32 + lg * 8);
    for (int i = 0; i < 4; ++i)
      for (int j = 0; j < 4; ++j)
        acc[i][j] = __builtin_amdgcn_mfma_f32_16x16x32_bf16(af[i], bfv[j], acc[i][j], 0, 0, 0);
  }
  for (int i = 0; i < 4; ++i)
    for (int j = 0; j < 4; ++j) {
      int col = n0 + wn + j * 16 + lr;
      for (int r = 0; r < 4; ++r) {
        int row = m0 + wm + i * 16 + lg * 4 + r;
        C[(size_t)row * N + col] = (OT)acc[i][j][r];
      }
    }
}

// ---------------- per-head RMSNorm + RoPE; one wave per (b,s,head24) ----------------
__global__ __launch_bounds__(256) void k_ropenorm(const bf16* __restrict__ qkv,
                                                  bf16* __restrict__ qb, bf16* __restrict__ kb,
                                                  const float* __restrict__ tbl,
                                                  const int* __restrict__ pos,
                                                  const float* __restrict__ qw,
                                                  const float* __restrict__ kw) {
  int gw = blockIdx.x * 4 + (threadIdx.x >> 6);
  int lane = threadIdx.x & 63;
  int h = gw % 24;
  int rem = gw / 24;
  int s = rem & (SS - 1);
  int b = rem >> 11;
  size_t row = (size_t)b * SS + s;
  int col0 = (h < 16) ? h * HD : QS + (h - 16) * HD;
  unsigned u = *(const unsigned*)(qkv + row * OC + col0 + lane * 2);
  float x0 = __uint_as_float((u & 0xffffu) << 16);
  float x1 = __uint_as_float(u & 0xffff0000u);
  float ssq = x0 * x0 + x1 * x1;
  for (int m = 1; m < 64; m <<= 1) ssq += __shfl_xor(ssq, m, 64);
  float r = rsqrtf(ssq * (1.0f / 128.0f) + 1e-6f);
  const float* wv = (h < 16) ? qw : kw;
  float y0 = x0 * r * wv[lane * 2], y1 = x1 * r * wv[lane * 2 + 1];
  float p0 = __shfl_xor(y0, 32, 64), p1 = __shfl_xor(y1, 32, 64);
  int p = pos[row];
  f32x4 cs = *(const f32x4*)(tbl + (size_t)p * 128 + (lane & 31) * 4); // c0,s0,c1,s1
  float o0, o1;
  if (lane < 32) { o0 = y0 * cs[0] - p0 * cs[1]; o1 = y1 * cs[2] - p1 * cs[3]; }
  else           { o0 = y0 * cs[0] + p0 * cs[1]; o1 = y1 * cs[2] + p1 * cs[3]; }
  bf16* dst; size_t drow;
  if (h < 16) { dst = qb; drow = ((size_t)b * NHEADS + h) * SS + s; }
  else        { dst = kb; drow = ((size_t)b * NKV + (h - 16)) * SS + s; }
  bf16 v0 = (bf16)o0, v1 = (bf16)o1;
  unsigned short q0, q1;
  __builtin_memcpy(&q0, &v0, 2); __builtin_memcpy(&q1, &v1, 2);
  *(unsigned*)(dst + drow * HD + lane * 2) = (unsigned)q0 | ((unsigned)q1 << 16);
}

// ---------------- simple correct flash attention (no MFMA) ----------------
__global__ __launch_bounds__(256) void k_attn2(const bf16* __restrict__ qb,
                                               const bf16* __restrict__ kb,
                                               const bf16* __restrict__ qkv,
                                               bf16* __restrict__ out) {
  const int lane = threadIdx.x & 63, w = threadIdx.x >> 6;
  const int s0 = (blockIdx.x * 4 + w) * 4;          // first of 4 q-rows
  const int h = blockIdx.y, b = blockIdx.z;
  const int kvh = h >> 1;
  __shared__ float qsh[4][4][128];                  // [wave][row][d]
  const bf16* qr = qb + ((size_t)(b * NHEADS + h) * SS + s0) * HD;
  for (int r = 0; r < 4; ++r) {
    unsigned u = *(const unsigned*)(qr + (size_t)r * HD + lane * 2);
    qsh[w][r][lane * 2]     = __uint_as_float((u & 0xffffu) << 16);
    qsh[w][r][lane * 2 + 1] = __uint_as_float(u & 0xffff0000u);
  }
  __syncthreads();
  float m[4], l[4], o0[4], o1[4];
  for (int r = 0; r < 4; ++r) { m[r] = -__builtin_inff(); l[r] = 0.f; o0[r] = 0.f; o1[r] = 0.f; }
  const bf16* Kg = kb + (size_t)(b * NKV + kvh) * SS * HD;
  const bf16* vbase = qkv + (size_t)b * SS * OC + QS + KVS + kvh * HD;
  const float scl = 0.08838834764831845f;           // 1/sqrt(128)
  const int ntile = ((s0 + 3) >> 6) + 1;
  for (int t = 0; t < ntile; ++t) {
    const int kv = t * 64 + lane;
    float a0 = 0.f, a1 = 0.f, a2 = 0.f, a3 = 0.f;
    {
      const bf16* kr = Kg + (size_t)kv * HD;
      for (int j = 0; j < 16; ++j) {
        bf16x8 k8 = *(const bf16x8*)(kr + j * 8);
        for (int e2 = 0; e2 < 2; ++e2) {
          f32x4 q0v = *(const f32x4*)&qsh[w][0][j * 8 + e2 * 4];
          f32x4 q1v = *(const f32x4*)&qsh[w][1][j * 8 + e2 * 4];
          f32x4 q2v = *(const f32x4*)&qsh[w][2][j * 8 + e2 * 4];
          f32x4 q3v = *(const f32x4*)&qsh[w][3][j * 8 + e2 * 4];
          for (int e = 0; e < 4; ++e) {
            float kf = (float)k8[e2 * 4 + e];
            a0 += kf * q0v[e];
            a1 += kf * q1v[e];
            a2 += kf * q2v[e];
            a3 += kf * q3v[e];
          }
        }
      }
    }
    float sc[4] = { a0 * scl, a1 * scl, a2 * scl, a3 * scl };
    float p[4];
    for (int r = 0; r < 4; ++r) {
      if (kv > s0 + r) sc[r] = -__builtin_inff();
      float pm = sc[r];
      for (int msk = 1; msk < 64; msk <<= 1) pm = fmaxf(pm, __shfl_xor(pm, msk, 64));
      float mn = fmaxf(m[r], pm);
      float scale = __expf(m[r] - mn);
      p[r] = __expf(sc[r] - mn);
      float ps = p[r];
      for (int msk = 1; msk < 64; msk <<= 1) ps += __shfl_xor(ps, msk, 64);
      l[r] = l[r] * scale + ps;
      m[r] = mn;
      o0[r] *= scale; o1[r] *= scale;
    }
    int kmax = s0 + 3 - t * 64 + 1;
    if (kmax > 64) kmax = 64;
    for (int k2 = 0; k2 < kmax; ++k2) {
      unsigned uv = *(const unsigned*)(vbase + (size_t)(t * 64 + k2) * OC + lane * 2);
      float v0 = __uint_as_float((uv & 0xffffu) << 16);
      float v1 = __uint_as_float(uv & 0xffff0000u);
      for (int r = 0; r < 4; ++r) {
        float pv = __shfl(p[r], k2, 64);
        o0[r] += pv * v0;
        o1[r] += pv * v1;
      }
    }
  }
  for (int r = 0; r < 4; ++r) {
    float inv = 1.0f / l[r];
    bf16 b0 = (bf16)(o0[r] * inv), b1 = (bf16)(o1[r] * inv);
    unsigned short u0, u1;
    __builtin_memcpy(&u0, &b0, 2); __builtin_memcpy(&u1, &b1, 2);
    *(unsigned*)(out + ((size_t)b * SS + s0 + r) * QS + h * HD + lane * 2)
        = (unsigned)u0 | ((unsigned)u1 << 16);
  }
}

// ---------------- launcher ----------------
extern "C" void kernel_launch(void* const* d_in, const int* in_sizes, int n_in,
                              void* d_out, int out_size, void* d_ws, size_t ws_size,
                              hipStream_t stream) {
  const int*   pos  = (const int*)d_in[0];
  const float* hid  = (const float*)d_in[1];
  const float* wqkv = (const float*)d_in[2];
  const float* wo   = (const float*)d_in[3];
  const float* qw   = (const float*)d_in[4];
  const float* kw   = (const float*)d_in[5];
  char* ws = (char*)d_ws;
  bf16* hid_bf  = (bf16*)(ws + 0);          // 16MB, reused as attn_out
  bf16* attn_o  = hid_bf;
  bf16* wqkv_bf = (bf16*)(ws + 16777216);   // 16MB, reused as q_buf
  bf16* q_buf   = wqkv_bf;
  bf16* k_buf   = (bf16*)(ws + 33554432);   // 8MB, reused as wo_bf
  bf16* wo_bf   = k_buf;
  bf16* qkv     = (bf16*)(ws + 41943040);   // 32MB
  float* tbl    = (float*)(ws + 83886080);  // 1MB

  k_cvt<<<dim3(2048), dim3(256), 0, stream>>>(hid,  hid_bf,  ROWS * HIDDEN / 8);
  k_cvt<<<dim3(2048), dim3(256), 0, stream>>>(wqkv, wqkv_bf, OC * HIDDEN / 8);
  k_table<<<dim3(512), dim3(256), 0, stream>>>(tbl);
  k_gemm<bf16><<<dim3(OC / 128, ROWS / 128), dim3(256), 0, stream>>>(
      hid_bf, wqkv_bf, qkv, ROWS, OC, HIDDEN);
  k_ropenorm<<<dim3(ROWS * 24 / 4), dim3(256), 0, stream>>>(
      qkv, q_buf, k_buf, tbl, pos, qw, kw);
  k_attn2<<<dim3(SS / 16, NHEADS, BB), dim3(256), 0, stream>>>(
      q_buf, k_buf, qkv, attn_o);
  k_cvt<<<dim3(2048), dim3(256), 0, stream>>>(wo, wo_bf, HIDDEN * QS / 8);
  k_gemm<float><<<dim3(HIDDEN / 128, ROWS / 128), dim3(256), 0, stream>>>(
      attn_o, wo_bf, (float*)d_out, ROWS, HIDDEN, QS);
}

// Round 7
// 2301.058 us; speedup vs baseline: 2.3528x; 2.3528x over previous
//
#include <hip/hip_runtime.h>
#include <hip/hip_bf16.h>
#include <cstdint>
#include <cstddef>

#define HIDDEN 2048
#define NHEADS 16
#define NKV    8
#define HD     128
#define QS     (NHEADS*HD)      // 2048
#define KVS    (NKV*HD)         // 1024
#define OC     (QS + 2*KVS)     // 4096
#define BB     2
#define SS     2048
#define ROWS   (BB*SS)          // 4096

typedef __bf16 bf16;
typedef __bf16 bf16x8 __attribute__((ext_vector_type(8)));
typedef float  f32x4  __attribute__((ext_vector_type(4)));
typedef float  f32x2  __attribute__((ext_vector_type(2)));
typedef int    i32x4  __attribute__((ext_vector_type(4)));

// ---------------- f32 -> bf16 convert (vectorized) ----------------
__global__ __launch_bounds__(256) void k_cvt(const float* __restrict__ src,
                                             bf16* __restrict__ dst, int n8) {
  int i = blockIdx.x * blockDim.x + threadIdx.x;
  int stride = gridDim.x * blockDim.x;
  for (; i < n8; i += stride) {
    const f32x4* s = (const f32x4*)(src + (size_t)i * 8);
    f32x4 a = s[0], b = s[1];
    bf16x8 o;
    o[0]=(bf16)a[0]; o[1]=(bf16)a[1]; o[2]=(bf16)a[2]; o[3]=(bf16)a[3];
    o[4]=(bf16)b[0]; o[5]=(bf16)b[1]; o[6]=(bf16)b[2]; o[7]=(bf16)b[3];
    *(bf16x8*)(dst + (size_t)i * 8) = o;
  }
}

// ---------------- RoPE cos/sin table: tbl[pos][i] = {cos, sin} ----------------
__global__ __launch_bounds__(256) void k_table(float* __restrict__ tbl) {
  int t = blockIdx.x * blockDim.x + threadIdx.x;   // t < SS*64
  int pos = t >> 6, i = t & 63;
  float freq = powf(10000.0f, -(float)i / 64.0f);
  float ang = (float)pos * freq;
  float sv, cv;
  sincosf(ang, &sv, &cv);
  f32x2 v; v[0] = cv; v[1] = sv;
  ((f32x2*)tbl)[t] = v;
}

// ---------------- async global->LDS helper ----------------
__device__ __forceinline__ void gll16(const void* g, void* l) {
  __builtin_amdgcn_global_load_lds((const __attribute__((address_space(1))) void*)g,
                                   (__attribute__((address_space(3))) void*)l, 16, 0, 0);
}

// ---------------- GEMM: C[M][N] = A[M][K] * Bw[N][K]^T  (bf16 in, f32 accum, OT out) ----------------
template <typename OT>
__global__ __launch_bounds__(256) void k_gemm(const bf16* __restrict__ A,
                                              const bf16* __restrict__ Bw,
                                              OT* __restrict__ C,
                                              int M, int N, int K) {
  const int tid = threadIdx.x;
  const int lane = tid & 63;
  const int w = tid >> 6;
  const int m0 = blockIdx.y * 128, n0 = blockIdx.x * 128;
  __shared__ bf16 As[128 * 32];
  __shared__ bf16 Bs[128 * 32];
  f32x4 acc[4][4] = {};
  const int wm = (w >> 1) * 64, wn = (w & 1) * 64;
  const int lr = lane & 15, lg = lane >> 4;
  const int KT = K >> 5;
  for (int kt = 0; kt < KT; ++kt) {
    __syncthreads();
    for (int i = 0; i < 2; ++i) {
      int c = tid + i * 256;
      int row = c >> 2, kc = c & 3;
      gll16(A + (size_t)(m0 + row) * K + kt * 32 + kc * 8, As + (size_t)(c & ~63) * 8);
      gll16(Bw + (size_t)(n0 + row) * K + kt * 32 + kc * 8, Bs + (size_t)(c & ~63) * 8);
    }
    asm volatile("s_waitcnt vmcnt(0)" ::: "memory");
    __syncthreads();
    bf16x8 af[4], bfv[4];
    for (int i = 0; i < 4; ++i)
      af[i] = *(const bf16x8*)(As + (wm + i * 16 + lr) * 32 + lg * 8);
    for (int j = 0; j < 4; ++j)
      bfv[j] = *(const bf16x8*)(Bs + (wn + j * 16 + lr) * 32 + lg * 8);
    for (int i = 0; i < 4; ++i)
      for (int j = 0; j < 4; ++j)
        acc[i][j] = __builtin_amdgcn_mfma_f32_16x16x32_bf16(af[i], bfv[j], acc[i][j], 0, 0, 0);
  }
  for (int i = 0; i < 4; ++i)
    for (int j = 0; j < 4; ++j) {
      int col = n0 + wn + j * 16 + lr;
      for (int r = 0; r < 4; ++r) {
        int row = m0 + wm + i * 16 + lg * 4 + r;
        C[(size_t)row * N + col] = (OT)acc[i][j][r];
      }
    }
}

// ---------------- per-head RMSNorm + RoPE; one wave per (b,s,head24) ----------------
__global__ __launch_bounds__(256) void k_ropenorm(const bf16* __restrict__ qkv,
                                                  bf16* __restrict__ qb, bf16* __restrict__ kb,
                                                  const float* __restrict__ tbl,
                                                  const int* __restrict__ pos,
                                                  const float* __restrict__ qw,
                                                  const float* __restrict__ kw) {
  int gw = blockIdx.x * 4 + (threadIdx.x >> 6);
  int lane = threadIdx.x & 63;
  int h = gw % 24;
  int rem = gw / 24;
  int s = rem & (SS - 1);
  int b = rem >> 11;
  size_t row = (size_t)b * SS + s;
  int col0 = (h < 16) ? h * HD : QS + (h - 16) * HD;
  unsigned u = *(const unsigned*)(qkv + row * OC + col0 + lane * 2);
  float x0 = __uint_as_float((u & 0xffffu) << 16);
  float x1 = __uint_as_float(u & 0xffff0000u);
  float ssq = x0 * x0 + x1 * x1;
  for (int m = 1; m < 64; m <<= 1) ssq += __shfl_xor(ssq, m, 64);
  float r = rsqrtf(ssq * (1.0f / 128.0f) + 1e-6f);
  const float* wv = (h < 16) ? qw : kw;
  float y0 = x0 * r * wv[lane * 2], y1 = x1 * r * wv[lane * 2 + 1];
  float p0 = __shfl_xor(y0, 32, 64), p1 = __shfl_xor(y1, 32, 64);
  int p = pos[row];
  f32x4 cs = *(const f32x4*)(tbl + (size_t)p * 128 + (lane & 31) * 4); // c0,s0,c1,s1
  float o0, o1;
  if (lane < 32) { o0 = y0 * cs[0] - p0 * cs[1]; o1 = y1 * cs[2] - p1 * cs[3]; }
  else           { o0 = y0 * cs[0] + p0 * cs[1]; o1 = y1 * cs[2] + p1 * cs[3]; }
  bf16* dst; size_t drow;
  if (h < 16) { dst = qb; drow = ((size_t)b * NHEADS + h) * SS + s; }
  else        { dst = kb; drow = ((size_t)b * NKV + (h - 16)) * SS + s; }
  bf16 v0 = (bf16)o0, v1 = (bf16)o1;
  unsigned short q0, q1;
  __builtin_memcpy(&q0, &v0, 2); __builtin_memcpy(&q1, &v1, 2);
  *(unsigned*)(dst + drow * HD + lane * 2) = (unsigned)q0 | ((unsigned)q1 << 16);
}

// ---------------- flash attention: MFMA QK^T + register softmax + SCALAR PV (bisect) ----------------
// 4 waves x 16 q-rows. Swapped QK^T (A=K rows, B=Q) via MFMA; P stays in registers;
// PV via __shfl broadcast (R3-verified pattern) reading V straight from qkv.
// Lane owns q-row = lr, d-slice = lg*32..lg*32+31. No LDS, no barriers.
__global__ __launch_bounds__(256) void k_attn3(const bf16* __restrict__ qb,
                                               const bf16* __restrict__ kb,
                                               const bf16* __restrict__ qkv,
                                               bf16* __restrict__ out) {
  const int lane = threadIdx.x & 63, w = threadIdx.x >> 6;
  const int qt = blockIdx.x, h = blockIdx.y, b = blockIdx.z;
  const int kvh = h >> 1;
  const int lr = lane & 15, lg = lane >> 4;
  const int qbase = qt * 64 + w * 16;
  const float NEG = -3.0e38f;
  bf16x8 qf[4];
  {
    const bf16* qrow = qb + ((size_t)(b * NHEADS + h) * SS + qbase + lr) * HD;
    #pragma unroll
    for (int ks = 0; ks < 4; ++ks) qf[ks] = *(const bf16x8*)(qrow + ks * 32 + lg * 8);
  }
  float o[32];
  #pragma unroll
  for (int dd = 0; dd < 32; ++dd) o[dd] = 0.f;
  float m_r = NEG, l_r = 0.0f;
  const bf16* Kg = kb + (size_t)(b * NKV + kvh) * SS * HD;
  const bf16* vb = qkv + (size_t)b * SS * OC + QS + KVS + kvh * HD + lg * 32;
  for (int t = 0; t <= qt; ++t) {
    const int kv0 = t * 64;
    // ---- QK^T: S^T[kv][q] via MFMA; K A-fragments from global (L2-hit) ----
    f32x4 sf[4];
    #pragma unroll
    for (int mt = 0; mt < 4; ++mt) {
      f32x4 a_ = {0.f, 0.f, 0.f, 0.f};
      const bf16* krow = Kg + (size_t)(kv0 + mt * 16 + lr) * HD;
      #pragma unroll
      for (int ks = 0; ks < 4; ++ks) {
        bf16x8 kf = *(const bf16x8*)(krow + ks * 32 + lg * 8);
        a_ = __builtin_amdgcn_mfma_f32_16x16x32_bf16(kf, qf[ks], a_, 0, 0, 0);
      }
      sf[mt] = a_;
    }
    // ---- scale + causal mask + online softmax (lane holds q=lr, kv=kv0+mt*16+lg*4+r) ----
    const float scl = 0.08838834764831845f;  // 1/sqrt(128)
    const int qg = qbase + lr;
    float pm = NEG;
    #pragma unroll
    for (int mt = 0; mt < 4; ++mt)
      #pragma unroll
      for (int r = 0; r < 4; ++r) {
        int kvg = kv0 + mt * 16 + lg * 4 + r;
        float v = sf[mt][r] * scl;
        if (kvg > qg) v = NEG;
        sf[mt][r] = v;
        pm = fmaxf(pm, v);
      }
    pm = fmaxf(pm, __shfl_xor(pm, 16, 64));
    pm = fmaxf(pm, __shfl_xor(pm, 32, 64));
    const float mn = fmaxf(m_r, pm);
    const float scale = __expf(m_r - mn);
    float ts = 0.f;
    #pragma unroll
    for (int mt = 0; mt < 4; ++mt)
      #pragma unroll
      for (int r = 0; r < 4; ++r) {
        float pv = __expf(sf[mt][r] - mn);     // masked -> 0
        sf[mt][r] = pv;
        ts += pv;
      }
    ts += __shfl_xor(ts, 16, 64);
    ts += __shfl_xor(ts, 32, 64);
    l_r = l_r * scale + ts;
    m_r = mn;
    // ---- rescale O (lane-local: this lane's o[] is row q=lr) ----
    #pragma unroll
    for (int dd = 0; dd < 32; ++dd) o[dd] *= scale;
    // ---- scalar PV: p broadcast from QK^T output registers; V direct from qkv ----
    // p for (q=lr, kv-local=k2) lives at lane ((k2>>2)&3)*16 + lr, reg sf[k2>>4][k2&3]
    #pragma unroll 8
    for (int k2 = 0; k2 < 64; ++k2) {
      float pv = __shfl(sf[k2 >> 4][k2 & 3], ((k2 >> 2) & 3) * 16 + lr, 64);
      const bf16* vr = vb + (size_t)(kv0 + k2) * OC;
      #pragma unroll
      for (int j = 0; j < 4; ++j) {
        bf16x8 v8 = *(const bf16x8*)(vr + j * 8);
        #pragma unroll
        for (int e = 0; e < 8; ++e) o[j * 8 + e] += pv * (float)v8[e];
      }
    }
  }
  const float inv = 1.0f / l_r;   // lane-local: row q=lr
  const size_t orow = ((size_t)b * SS + qbase + lr) * QS + h * HD + lg * 32;
  #pragma unroll
  for (int j = 0; j < 4; ++j) {
    bf16x8 ov;
    #pragma unroll
    for (int e = 0; e < 8; ++e) ov[e] = (bf16)(o[j * 8 + e] * inv);
    *(bf16x8*)(out + orow + j * 8) = ov;
  }
}

// ---------------- launcher ----------------
extern "C" void kernel_launch(void* const* d_in, const int* in_sizes, int n_in,
                              void* d_out, int out_size, void* d_ws, size_t ws_size,
                              hipStream_t stream) {
  const int*   pos  = (const int*)d_in[0];
  const float* hid  = (const float*)d_in[1];
  const float* wqkv = (const float*)d_in[2];
  const float* wo   = (const float*)d_in[3];
  const float* qw   = (const float*)d_in[4];
  const float* kw   = (const float*)d_in[5];
  char* ws = (char*)d_ws;
  bf16* hid_bf  = (bf16*)(ws + 0);          // 16MB, reused as attn_out
  bf16* attn_o  = hid_bf;
  bf16* wqkv_bf = (bf16*)(ws + 16777216);   // 16MB, reused as q_buf
  bf16* q_buf   = wqkv_bf;
  bf16* k_buf   = (bf16*)(ws + 33554432);   // 8MB, reused as wo_bf
  bf16* wo_bf   = k_buf;
  bf16* qkv     = (bf16*)(ws + 41943040);   // 32MB
  float* tbl    = (float*)(ws + 83886080);  // 1MB

  k_cvt<<<dim3(2048), dim3(256), 0, stream>>>(hid,  hid_bf,  ROWS * HIDDEN / 8);
  k_cvt<<<dim3(2048), dim3(256), 0, stream>>>(wqkv, wqkv_bf, OC * HIDDEN / 8);
  k_table<<<dim3(512), dim3(256), 0, stream>>>(tbl);
  k_gemm<bf16><<<dim3(OC / 128, ROWS / 128), dim3(256), 0, stream>>>(
      hid_bf, wqkv_bf, qkv, ROWS, OC, HIDDEN);
  k_ropenorm<<<dim3(ROWS * 24 / 4), dim3(256), 0, stream>>>(
      qkv, q_buf, k_buf, tbl, pos, qw, kw);
  k_attn3<<<dim3(SS / 64, NHEADS, BB), dim3(256), 0, stream>>>(
      q_buf, k_buf, qkv, attn_o);
  k_cvt<<<dim3(2048), dim3(256), 0, stream>>>(wo, wo_bf, HIDDEN * QS / 8);
  k_gemm<float><<<dim3(HIDDEN / 128, ROWS / 128), dim3(256), 0, stream>>>(
      attn_o, wo_bf, (float*)d_out, ROWS, HIDDEN, QS);
}

// Round 9
// 638.250 us; speedup vs baseline: 8.4825x; 3.6053x over previous
//
#include <hip/hip_runtime.h>
#include <hip/hip_bf16.h>
#include <cstdint>
#include <cstddef>

#define HIDDEN 2048
#define NHEADS 16
#define NKV    8
#define HD     128
#define QS     (NHEADS*HD)      // 2048
#define KVS    (NKV*HD)         // 1024
#define OC     (QS + 2*KVS)     // 4096
#define BB     2
#define SS     2048
#define ROWS   (BB*SS)          // 4096

typedef __bf16 bf16;
typedef __bf16 bf16x8 __attribute__((ext_vector_type(8)));
typedef float  f32x4  __attribute__((ext_vector_type(4)));
typedef float  f32x2  __attribute__((ext_vector_type(2)));
typedef int    i32x4  __attribute__((ext_vector_type(4)));

// ---------------- f32 -> bf16 convert (vectorized) ----------------
__global__ __launch_bounds__(256) void k_cvt(const float* __restrict__ src,
                                             bf16* __restrict__ dst, int n8) {
  int i = blockIdx.x * blockDim.x + threadIdx.x;
  int stride = gridDim.x * blockDim.x;
  for (; i < n8; i += stride) {
    const f32x4* s = (const f32x4*)(src + (size_t)i * 8);
    f32x4 a = s[0], b = s[1];
    bf16x8 o;
    o[0]=(bf16)a[0]; o[1]=(bf16)a[1]; o[2]=(bf16)a[2]; o[3]=(bf16)a[3];
    o[4]=(bf16)b[0]; o[5]=(bf16)b[1]; o[6]=(bf16)b[2]; o[7]=(bf16)b[3];
    *(bf16x8*)(dst + (size_t)i * 8) = o;
  }
}

// ---------------- RoPE cos/sin table: tbl[pos][i] = {cos, sin} ----------------
__global__ __launch_bounds__(256) void k_table(float* __restrict__ tbl) {
  int t = blockIdx.x * blockDim.x + threadIdx.x;   // t < SS*64
  int pos = t >> 6, i = t & 63;
  float freq = powf(10000.0f, -(float)i / 64.0f);
  float ang = (float)pos * freq;
  float sv, cv;
  sincosf(ang, &sv, &cv);
  f32x2 v; v[0] = cv; v[1] = sv;
  ((f32x2*)tbl)[t] = v;
}

// ---------------- async global->LDS helper ----------------
__device__ __forceinline__ void gll16(const void* g, void* l) {
  __builtin_amdgcn_global_load_lds((const __attribute__((address_space(1))) void*)g,
                                   (__attribute__((address_space(3))) void*)l, 16, 0, 0);
}

// ---------------- GEMM: C[M][N] = A[M][K] * Bw[N][K]^T  (bf16 in, f32 accum, OT out) ----------------
template <typename OT>
__global__ __launch_bounds__(256) void k_gemm(const bf16* __restrict__ A,
                                              const bf16* __restrict__ Bw,
                                              OT* __restrict__ C,
                                              int M, int N, int K) {
  const int tid = threadIdx.x;
  const int lane = tid & 63;
  const int w = tid >> 6;
  const int m0 = blockIdx.y * 128, n0 = blockIdx.x * 128;
  __shared__ bf16 As[128 * 32];
  __shared__ bf16 Bs[128 * 32];
  f32x4 acc[4][4] = {};
  const int wm = (w >> 1) * 64, wn = (w & 1) * 64;
  const int lr = lane & 15, lg = lane >> 4;
  const int KT = K >> 5;
  for (int kt = 0; kt < KT; ++kt) {
    __syncthreads();
    for (int i = 0; i < 2; ++i) {
      int c = tid + i * 256;
      int row = c >> 2, kc = c & 3;
      gll16(A + (size_t)(m0 + row) * K + kt * 32 + kc * 8, As + (size_t)(c & ~63) * 8);
      gll16(Bw + (size_t)(n0 + row) * K + kt * 32 + kc * 8, Bs + (size_t)(c & ~63) * 8);
    }
    asm volatile("s_waitcnt vmcnt(0)" ::: "memory");
    __syncthreads();
    bf16x8 af[4], bfv[4];
    for (int i = 0; i < 4; ++i)
      af[i] = *(const bf16x8*)(As + (wm + i * 16 + lr) * 32 + lg * 8);
    for (int j = 0; j < 4; ++j)
      bfv[j] = *(const bf16x8*)(Bs + (wn + j * 16 + lr) * 32 + lg * 8);
    for (int i = 0; i < 4; ++i)
      for (int j = 0; j < 4; ++j)
        acc[i][j] = __builtin_amdgcn_mfma_f32_16x16x32_bf16(af[i], bfv[j], acc[i][j], 0, 0, 0);
  }
  for (int i = 0; i < 4; ++i)
    for (int j = 0; j < 4; ++j) {
      int col = n0 + wn + j * 16 + lr;
      for (int r = 0; r < 4; ++r) {
        int row = m0 + wm + i * 16 + lg * 4 + r;
        C[(size_t)row * N + col] = (OT)acc[i][j][r];
      }
    }
}

// ---------------- per-head RMSNorm + RoPE; one wave per (b,s,head24) ----------------
__global__ __launch_bounds__(256) void k_ropenorm(const bf16* __restrict__ qkv,
                                                  bf16* __restrict__ qb, bf16* __restrict__ kb,
                                                  const float* __restrict__ tbl,
                                                  const int* __restrict__ pos,
                                                  const float* __restrict__ qw,
                                                  const float* __restrict__ kw) {
  int gw = blockIdx.x * 4 + (threadIdx.x >> 6);
  int lane = threadIdx.x & 63;
  int h = gw % 24;
  int rem = gw / 24;
  int s = rem & (SS - 1);
  int b = rem >> 11;
  size_t row = (size_t)b * SS + s;
  int col0 = (h < 16) ? h * HD : QS + (h - 16) * HD;
  unsigned u = *(const unsigned*)(qkv + row * OC + col0 + lane * 2);
  float x0 = __uint_as_float((u & 0xffffu) << 16);
  float x1 = __uint_as_float(u & 0xffff0000u);
  float ssq = x0 * x0 + x1 * x1;
  for (int m = 1; m < 64; m <<= 1) ssq += __shfl_xor(ssq, m, 64);
  float r = rsqrtf(ssq * (1.0f / 128.0f) + 1e-6f);
  const float* wv = (h < 16) ? qw : kw;
  float y0 = x0 * r * wv[lane * 2], y1 = x1 * r * wv[lane * 2 + 1];
  float p0 = __shfl_xor(y0, 32, 64), p1 = __shfl_xor(y1, 32, 64);
  int p = pos[row];
  f32x4 cs = *(const f32x4*)(tbl + (size_t)p * 128 + (lane & 31) * 4); // c0,s0,c1,s1
  float o0, o1;
  if (lane < 32) { o0 = y0 * cs[0] - p0 * cs[1]; o1 = y1 * cs[2] - p1 * cs[3]; }
  else           { o0 = y0 * cs[0] + p0 * cs[1]; o1 = y1 * cs[2] + p1 * cs[3]; }
  bf16* dst; size_t drow;
  if (h < 16) { dst = qb; drow = ((size_t)b * NHEADS + h) * SS + s; }
  else        { dst = kb; drow = ((size_t)b * NKV + (h - 16)) * SS + s; }
  bf16 v0 = (bf16)o0, v1 = (bf16)o1;
  unsigned short q0, q1;
  __builtin_memcpy(&q0, &v0, 2); __builtin_memcpy(&q1, &v1, 2);
  *(unsigned*)(dst + drow * HD + lane * 2) = (unsigned)q0 | ((unsigned)q1 << 16);
}

// ---------------- flash attention: full-MFMA, K and V fragments from global, no LDS ----------------
// 4 waves x 16 q-rows. Swapped QK^T (A=K rows, B=Q). P regrouped in-register via
// two-shfl broadcast (register index must be SOURCE-lane-uniform!); V B-fragments
// gathered directly from qkv (L1/L2-hit).
__global__ __launch_bounds__(256) void k_attn4(const bf16* __restrict__ qb,
                                               const bf16* __restrict__ kb,
                                               const bf16* __restrict__ qkv,
                                               bf16* __restrict__ out) {
  const int lane = threadIdx.x & 63, w = threadIdx.x >> 6;
  const int qt = blockIdx.x, h = blockIdx.y, b = blockIdx.z;
  const int kvh = h >> 1;
  const int lr = lane & 15, lg = lane >> 4;
  const int qbase = qt * 64 + w * 16;
  const float NEG = -3.0e38f;
  bf16x8 qf[4];
  {
    const bf16* qrow = qb + ((size_t)(b * NHEADS + h) * SS + qbase + lr) * HD;
    #pragma unroll
    for (int ks = 0; ks < 4; ++ks) qf[ks] = *(const bf16x8*)(qrow + ks * 32 + lg * 8);
  }
  f32x4 acc[8] = {};                 // acc[nt][r] = O[q=lg*4+r][d=nt*16+lr]
  float m_r = NEG, l_r = 0.0f;
  const bf16* Kg = kb + (size_t)(b * NKV + kvh) * SS * HD;
  const bf16* Vb = qkv + (size_t)b * SS * OC + QS + KVS + kvh * HD;
  for (int t = 0; t <= qt; ++t) {
    const int kv0 = t * 64;
    // ---- QK^T: S^T[kv][q] via MFMA; K A-fragments from global (L2-hit) ----
    f32x4 sf[4];
    #pragma unroll
    for (int mt = 0; mt < 4; ++mt) {
      f32x4 a_ = {0.f, 0.f, 0.f, 0.f};
      const bf16* krow = Kg + (size_t)(kv0 + mt * 16 + lr) * HD;
      #pragma unroll
      for (int ks = 0; ks < 4; ++ks) {
        bf16x8 kf = *(const bf16x8*)(krow + ks * 32 + lg * 8);
        a_ = __builtin_amdgcn_mfma_f32_16x16x32_bf16(kf, qf[ks], a_, 0, 0, 0);
      }
      sf[mt] = a_;
    }
    // ---- scale + causal mask + online softmax (lane holds q=lr, kv=kv0+mt*16+lg*4+r) ----
    const float scl = 0.08838834764831845f;  // 1/sqrt(128)
    const int qg = qbase + lr;
    float pm = NEG;
    #pragma unroll
    for (int mt = 0; mt < 4; ++mt)
      #pragma unroll
      for (int r = 0; r < 4; ++r) {
        int kvg = kv0 + mt * 16 + lg * 4 + r;
        float v = sf[mt][r] * scl;
        if (kvg > qg) v = NEG;
        sf[mt][r] = v;
        pm = fmaxf(pm, v);
      }
    pm = fmaxf(pm, __shfl_xor(pm, 16, 64));
    pm = fmaxf(pm, __shfl_xor(pm, 32, 64));
    const float mn = fmaxf(m_r, pm);
    const float scale = __expf(m_r - mn);
    float ts = 0.f;
    #pragma unroll
    for (int mt = 0; mt < 4; ++mt)
      #pragma unroll
      for (int r = 0; r < 4; ++r) {
        float pv = __expf(sf[mt][r] - mn);     // masked -> 0
        sf[mt][r] = pv;
        ts += pv;
      }
    ts += __shfl_xor(ts, 16, 64);
    ts += __shfl_xor(ts, 32, 64);
    l_r = l_r * scale + ts;
    m_r = mn;
    // ---- rescale O: acc row q' = lg*4+r; lane lg*4+r has lr == q' ----
    float sr[4];
    #pragma unroll
    for (int r = 0; r < 4; ++r) sr[r] = __shfl(scale, lg * 4 + r, 64);
    #pragma unroll
    for (int nt = 0; nt < 8; ++nt)
      #pragma unroll
      for (int r = 0; r < 4; ++r) acc[nt][r] *= sr[r];
    // ---- PV: regroup P in-register to A-fragment layout ----
    // source: sf[mt][r] on lane (lr,lg) = P[q=lr][kv=mt*16+lg*4+r]
    // target: pa[j] on lane (lr,lg) = P[q=lr][kv=kk*32+lg*8+j]
    //   src lane = ((lg&1)*2+(j>>2))*16 + lr; src reg = sf[2kk+(lg>>1)][j&3]
    // Register index must be uniform in the shfl operand (evaluated on the
    // SOURCE lane) -> broadcast both candidates, pick by dest's lg.
    #pragma unroll
    for (int kk = 0; kk < 2; ++kk) {
      bf16x8 pa;
      #pragma unroll
      for (int j = 0; j < 8; ++j) {
        int srclane = ((lg & 1) * 2 + (j >> 2)) * 16 + lr;
        float v0 = __shfl(sf[2 * kk][j & 3], srclane, 64);
        float v1 = __shfl(sf[2 * kk + 1][j & 3], srclane, 64);
        pa[j] = (bf16)((lg & 2) ? v1 : v0);
      }
      #pragma unroll
      for (int nt = 0; nt < 8; ++nt) {
        // vb[j] = V[kv0+kk*32+lg*8+j][nt*16+lr]  (B[k][col] fragment)
        const bf16* vcol = Vb + (size_t)(kv0 + kk * 32 + lg * 8) * OC + nt * 16 + lr;
        bf16x8 vbf;
        #pragma unroll
        for (int j = 0; j < 8; ++j) vbf[j] = vcol[(size_t)j * OC];
        acc[nt] = __builtin_amdgcn_mfma_f32_16x16x32_bf16(pa, vbf, acc[nt], 0, 0, 0);
      }
    }
  }
  // ---- epilogue: normalize rows and store (k_gemm's verified store pattern) ----
  const float inv = 1.0f / l_r;     // lane holds inv for q=lr
  float ir[4];
  #pragma unroll
  for (int r = 0; r < 4; ++r) ir[r] = __shfl(inv, lg * 4 + r, 64);
  #pragma unroll
  for (int nt = 0; nt < 8; ++nt)
    #pragma unroll
    for (int r = 0; r < 4; ++r) {
      size_t row = (size_t)b * SS + qbase + lg * 4 + r;
      out[row * QS + h * HD + nt * 16 + lr] = (bf16)(acc[nt][r] * ir[r]);
    }
}

// ---------------- launcher ----------------
extern "C" void kernel_launch(void* const* d_in, const int* in_sizes, int n_in,
                              void* d_out, int out_size, void* d_ws, size_t ws_size,
                              hipStream_t stream) {
  const int*   pos  = (const int*)d_in[0];
  const float* hid  = (const float*)d_in[1];
  const float* wqkv = (const float*)d_in[2];
  const float* wo   = (const float*)d_in[3];
  const float* qw   = (const float*)d_in[4];
  const float* kw   = (const float*)d_in[5];
  char* ws = (char*)d_ws;
  bf16* hid_bf  = (bf16*)(ws + 0);          // 16MB, reused as attn_out
  bf16* attn_o  = hid_bf;
  bf16* wqkv_bf = (bf16*)(ws + 16777216);   // 16MB, reused as q_buf
  bf16* q_buf   = wqkv_bf;
  bf16* k_buf   = (bf16*)(ws + 33554432);   // 8MB, reused as wo_bf
  bf16* wo_bf   = k_buf;
  bf16* qkv     = (bf16*)(ws + 41943040);   // 32MB
  float* tbl    = (float*)(ws + 83886080);  // 1MB

  k_cvt<<<dim3(2048), dim3(256), 0, stream>>>(hid,  hid_bf,  ROWS * HIDDEN / 8);
  k_cvt<<<dim3(2048), dim3(256), 0, stream>>>(wqkv, wqkv_bf, OC * HIDDEN / 8);
  k_table<<<dim3(512), dim3(256), 0, stream>>>(tbl);
  k_gemm<bf16><<<dim3(OC / 128, ROWS / 128), dim3(256), 0, stream>>>(
      hid_bf, wqkv_bf, qkv, ROWS, OC, HIDDEN);
  k_ropenorm<<<dim3(ROWS * 24 / 4), dim3(256), 0, stream>>>(
      qkv, q_buf, k_buf, tbl, pos, qw, kw);
  k_attn4<<<dim3(SS / 64, NHEADS, BB), dim3(256), 0, stream>>>(
      q_buf, k_buf, qkv, attn_o);
  k_cvt<<<dim3(2048), dim3(256), 0, stream>>>(wo, wo_bf, HIDDEN * QS / 8);
  k_gemm<float><<<dim3(HIDDEN / 128, ROWS / 128), dim3(256), 0, stream>>>(
      attn_o, wo_bf, (float*)d_out, ROWS, HIDDEN, QS);
}